// Round 1
// baseline (12462.908 us; speedup 1.0000x reference)
//
#include <hip/hip_runtime.h>

typedef _Float16 f16;
typedef _Float16 f16x4 __attribute__((ext_vector_type(4)));
typedef _Float16 f16x8 __attribute__((ext_vector_type(8)));
typedef float    f32x4 __attribute__((ext_vector_type(4)));

#define NN 1024
#define NB 64
#define NT 12
#define NHOR 12
#define ROWS (NN*NB)                 // 65536 (n*64+b)
static const long SLOT = (long)ROWS*64;   // one diffusion slot (N,B,64)

#define LDA_S 40     // As LDS row stride in halves ([m][k])
#define LDZ_S 136    // Zs LDS row stride in halves ([k][c])

// ---------------------------------------------------------------- diffusion GEMM
// out(M x C) = A(M x 1024) @ Z(1024 x C), fp16 in, f32 acc, fp16 out.
// Z/out split into two column ranges (h-part / x-part).
struct DiffP {
  const f16* A;
  const f16* z1; long ldz1; int nct1; f16* o1; long ldo1;
  const f16* z2; long ldz2; int nct2; f16* o2; long ldo2; int cv2;
  int K; int matsq;   // matsq: out = 2*acc - I (for W = 2A^2 - I)
};

__global__ __launch_bounds__(256) void gemm_diff(DiffP p) {
  __shared__ f16 As[128*LDA_S];
  __shared__ f16 Zs[32*LDZ_S];
  const int rt = blockIdx.x, ct = blockIdx.y;
  const f16* zptr; long ldz; f16* optr; long ldo; int cvalid; long c0;
  if (ct < p.nct1) { c0=(long)ct*128; zptr=p.z1; ldz=p.ldz1; optr=p.o1; ldo=p.ldo1; cvalid=128; }
  else { c0=(long)(ct-p.nct1)*128; zptr=p.z2; ldz=p.ldz2; optr=p.o2; ldo=p.ldo2; cvalid=p.cv2; }
  const int tid=threadIdx.x, lane=tid&63, wv=tid>>6;
  const int wm=(wv>>1)*64, wc=(wv&1)*64;
  const int rq=lane>>4, ro=lane&15, lk=rq*4;
  f32x4 acc[4][4] = {};
  const long r0 = (long)rt*128;
  for (int k0=0; k0<p.K; k0+=32) {
    #pragma unroll
    for (int it=0; it<2; ++it) {            // A tile: 128 rows x 32 k
      const int t = tid + it*256;
      const int m = t>>2, sg = t&3;
      f16x8 v = *(const f16x8*)(p.A + (r0+m)*1024 + k0 + sg*8);
      *(f16x8*)(&As[m*LDA_S + sg*8]) = v;
    }
    #pragma unroll
    for (int it=0; it<2; ++it) {            // Z tile: 32 k x 128 c (k-major)
      const int t = tid + it*256;
      const int kz = t>>4, c8 = t&15;
      if (c8*8 < cvalid) {
        f16x8 v = *(const f16x8*)(zptr + (long)(k0+kz)*ldz + c0 + c8*8);
        *(f16x8*)(&Zs[kz*LDZ_S + c8*8]) = v;
      }
    }
    __syncthreads();
    f16x8 a[4], b[4];
    #pragma unroll
    for (int i=0;i<4;i++) {
      const f16* ar = &As[(wm + i*16 + ro)*LDA_S + lk];
      f16x4 lo = *(const f16x4*)ar;
      f16x4 hi = *(const f16x4*)(ar + 16);
      f16x8 t2; t2[0]=lo[0];t2[1]=lo[1];t2[2]=lo[2];t2[3]=lo[3];
      t2[4]=hi[0];t2[5]=hi[1];t2[6]=hi[2];t2[7]=hi[3];
      a[i]=t2;
    }
    #pragma unroll
    for (int j=0;j<4;j++) {
      const int c = wc + j*16 + ro;
      f16x8 t2;
      #pragma unroll
      for (int jj=0;jj<4;jj++) t2[jj]   = Zs[(lk+jj)*LDZ_S + c];
      #pragma unroll
      for (int jj=0;jj<4;jj++) t2[4+jj] = Zs[(16+lk+jj)*LDZ_S + c];
      b[j]=t2;
    }
    #pragma unroll
    for (int i=0;i<4;i++)
      #pragma unroll
      for (int j=0;j<4;j++)
        acc[i][j] = __builtin_amdgcn_mfma_f32_16x16x32_f16(a[i], b[j], acc[i][j], 0,0,0);
    __syncthreads();
  }
  #pragma unroll
  for (int i=0;i<4;i++) {
    #pragma unroll
    for (int j=0;j<4;j++) {
      const int col = wc + j*16 + ro;
      if (col >= cvalid) continue;
      const long cg = c0 + col;
      #pragma unroll
      for (int e=0;e<4;e++) {
        const long rg = r0 + wm + i*16 + rq*4 + e;
        float v = acc[i][j][e];
        if (p.matsq) v = 2.f*v - ((rg==cg)?1.f:0.f);
        optr[rg*ldo + cg] = (f16)v;
      }
    }
  }
}

// ---------------------------------------------------------------- cell GEMMs
// rows = (n*64+b), K = nseg*320 gathered over 5 diffusion slots, cols = O.
struct Tab5 { const f16* p[5]; };
struct CellP {
  Tab5 ta, tb, xq;
  const f16 *wa, *wb, *wx0;
  const float* bias;
  const float* h32in;           // gate: h (f32 master) for rh = r*h
  f16* rh; float* u32;
  float* h32io; f16* h16io;     // cand: GRU update in/out
  int nseg, xf1;
};

template<int O, int GATE>
__global__ __launch_bounds__(256) void cell_gemm(CellP p) {
  constexpr int FC = O/32;
  constexpr int C8 = O/8;
  __shared__ f16 As[128*LDA_S];
  __shared__ f16 Zs[32*LDZ_S];
  const int tid=threadIdx.x, lane=tid&63, wv=tid>>6;
  const int wm=(wv>>1)*64, wc=(wv&1)*(O/2);
  const int rq=lane>>4, ro=lane&15, lk=rq*4;
  f32x4 acc[4][FC] = {};
  const long r0 = (long)blockIdx.x*128;
  const int Ktot = p.nseg*320;
  for (int kg=0; kg<Ktot; kg+=32) {
    const int seg = (kg>=320)?1:0;
    const int kk  = kg - seg*320;
    const int q = kk>>6, kq = kk&63;
    const f16* asrc = seg ? p.tb.p[q] : p.ta.p[q];
    const f16* wsrc = (seg ? p.wb : p.wa) + (long)kk*O;
    #pragma unroll
    for (int it=0; it<2; ++it) {
      const int t = tid + it*256;
      const int m = t>>2, sg = t&3;
      f16x8 v = *(const f16x8*)(asrc + (r0+m)*64 + kq + sg*8);
      *(f16x8*)(&As[m*LDA_S + sg*8]) = v;
    }
    #pragma unroll
    for (int it=0; it<(32*C8)/256; ++it) {
      const int t = tid + it*256;
      const int kz = t/C8, c8 = t%C8;
      f16x8 v = *(const f16x8*)(wsrc + (long)kz*O + c8*8);
      *(f16x8*)(&Zs[kz*LDZ_S + c8*8]) = v;
    }
    __syncthreads();
    f16x8 a[4], b[FC];
    #pragma unroll
    for (int i=0;i<4;i++) {
      const f16* ar = &As[(wm + i*16 + ro)*LDA_S + lk];
      f16x4 lo = *(const f16x4*)ar;
      f16x4 hi = *(const f16x4*)(ar + 16);
      f16x8 t2; t2[0]=lo[0];t2[1]=lo[1];t2[2]=lo[2];t2[3]=lo[3];
      t2[4]=hi[0];t2[5]=hi[1];t2[6]=hi[2];t2[7]=hi[3];
      a[i]=t2;
    }
    #pragma unroll
    for (int j=0;j<FC;j++) {
      const int c = wc + j*16 + ro;
      f16x8 t2;
      #pragma unroll
      for (int jj=0;jj<4;jj++) t2[jj]   = Zs[(lk+jj)*LDZ_S + c];
      #pragma unroll
      for (int jj=0;jj<4;jj++) t2[4+jj] = Zs[(16+lk+jj)*LDZ_S + c];
      b[j]=t2;
    }
    #pragma unroll
    for (int i=0;i<4;i++)
      #pragma unroll
      for (int j=0;j<FC;j++)
        acc[i][j] = __builtin_amdgcn_mfma_f32_16x16x32_f16(a[i], b[j], acc[i][j], 0,0,0);
    __syncthreads();
  }
  #pragma unroll
  for (int i=0;i<4;i++) {
    #pragma unroll
    for (int e=0;e<4;e++) {
      const long rg = r0 + wm + i*16 + rq*4 + e;
      float xv[5];
      if (p.xf1) {
        #pragma unroll
        for (int q2=0;q2<5;q2++) xv[q2] = (float)p.xq.p[q2][rg];
      }
      #pragma unroll
      for (int j=0;j<FC;j++) {
        const int col = wc + j*16 + ro;
        float v = acc[i][j][e] + p.bias[col];
        if (p.xf1) {
          #pragma unroll
          for (int q2=0;q2<5;q2++) v += xv[q2] * (float)p.wx0[q2*O + col];
        }
        if (GATE) {
          const float s = 1.f/(1.f + __expf(-v));
          if (col < 64) p.rh[rg*64 + col] = (f16)(s * p.h32in[rg*64 + col]);
          else          p.u32[rg*64 + (col-64)] = s;
        } else {
          const float cc = tanhf(v);
          const float u  = p.u32[rg*64 + col];
          const float h  = p.h32io[rg*64 + col];
          const float hn = u*h + (1.f-u)*cc;
          p.h32io[rg*64 + col] = hn;
          p.h16io[rg*64 + col] = (f16)hn;
        }
      }
    }
  }
}

// ---------------------------------------------------------------- small kernels
__global__ void k_cast_sup(const float* s, f16* W) {
  long i = (long)blockIdx.x*256 + threadIdx.x;
  if (i >= 2LL*NN*NN) return;
  long ss = (i >= (long)NN*NN) ? 1 : 0;
  long off = i - ss*(long)NN*NN;
  W[ss*2*(long)NN*NN + off] = (f16)s[i];
}

__global__ void k_pack_x(const float* in, f16* xe) {
  int i = blockIdx.x*256 + threadIdx.x;
  if (i >= NT*ROWS) return;
  int t = i / ROWS, r = i % ROWS, n = r>>6, b = r&63;
  xe[i] = (f16)in[(long)b*NN*NT + (long)n*NT + t];
}

__global__ void k_split_w(const float* src, f16* dsth, f16* dstx, int f, int xf, int O) {
  int i = blockIdx.x*256 + threadIdx.x;
  if (i >= 5*f*O) return;
  int o = i % O, rr = i / O, q = rr / f, ff = rr % f;
  f16 v = (f16)src[i];
  if (ff < xf) dstx[(q*xf + ff)*O + o] = v;
  else         dsth[(q*64 + ff - xf)*O + o] = v;
}

__global__ void k_proj(const float* h32, const float* pw, const float* pb,
                       float* out, f16* xdec) {
  int r = blockIdx.x*256 + threadIdx.x;
  if (r >= ROWS) return;
  float acc = pb[0];
  const float* hp = h32 + (long)r*64;
  #pragma unroll
  for (int k=0;k<64;k++) acc += hp[k]*pw[k];
  int n = r>>6, b = r&63;
  out[(long)b*NN + n] = acc;
  xdec[r] = (f16)acc;
}

// ---------------------------------------------------------------- driver
extern "C" void kernel_launch(void* const* d_in, const int* in_sizes, int n_in,
                              void* d_out, int out_size, void* d_ws, size_t ws_size,
                              hipStream_t stream) {
  (void)in_sizes; (void)n_in; (void)out_size; (void)ws_size;
  const float* inputs = (const float*)d_in[0];
  const float* sup    = (const float*)d_in[1];
  const float* gwp[4] = {(const float*)d_in[2], (const float*)d_in[6], (const float*)d_in[10], (const float*)d_in[14]};
  const float* gbp[4] = {(const float*)d_in[3], (const float*)d_in[7], (const float*)d_in[11], (const float*)d_in[15]};
  const float* cwp[4] = {(const float*)d_in[4], (const float*)d_in[8], (const float*)d_in[12], (const float*)d_in[16]};
  const float* cbp[4] = {(const float*)d_in[5], (const float*)d_in[9], (const float*)d_in[13], (const float*)d_in[17]};
  const float* pw = (const float*)d_in[18];
  const float* pb = (const float*)d_in[19];
  float* out = (float*)d_out;

  char* base = (char*)d_ws; size_t off = 0;
  auto alloc = [&](size_t bytes)->void* { void* p = base + off; off += (bytes + 255) & ~(size_t)255; return p; };
  f16* W16   = (f16*)alloc(4LL*NN*NN*2);        // [A0, 2A0^2-I, A1, 2A1^2-I]
  f16* xenc  = (f16*)alloc((long)NT*ROWS*2);
  f16* xdec  = (f16*)alloc((long)ROWS*2);
  f16*  h16[2] = {(f16*)alloc(SLOT*2),  (f16*)alloc(SLOT*2)};
  float* h32[2] = {(float*)alloc(SLOT*4), (float*)alloc(SLOT*4)};
  float* u32 = (float*)alloc(SLOT*4);
  f16* rh    = (f16*)alloc(SLOT*2);
  f16* Dh    = (f16*)alloc(4*SLOT*2);
  f16* Dx    = (f16*)alloc(4*SLOT*2);
  f16* Dx0   = (f16*)alloc(4LL*ROWS*2);
  f16 *gwh[4], *gwx[4], *cwh[4], *cwx[4];
  for (int i=0;i<4;i++) {
    gwh[i]=(f16*)alloc(5*64*128*2); gwx[i]=(f16*)alloc(5*64*128*2);
    cwh[i]=(f16*)alloc(5*64*64*2);  cwx[i]=(f16*)alloc(5*64*64*2);
  }

  hipMemsetAsync(h16[0], 0, SLOT*2, stream);
  hipMemsetAsync(h16[1], 0, SLOT*2, stream);
  hipMemsetAsync(h32[0], 0, SLOT*4, stream);
  hipMemsetAsync(h32[1], 0, SLOT*4, stream);
  hipMemsetAsync(xdec,   0, (long)ROWS*2, stream);

  k_cast_sup<<<(2*NN*NN+255)/256, 256, 0, stream>>>(sup, W16);
  for (int s=0;s<2;s++) {   // W[2s+1] = 2*A_s^2 - I
    DiffP mp{};
    mp.A = W16 + (long)s*2*NN*NN;
    mp.z1 = mp.A; mp.ldz1 = 1024; mp.nct1 = 8;
    mp.o1 = W16 + ((long)s*2+1)*NN*NN; mp.ldo1 = 1024;
    mp.nct2 = 0; mp.K = 1024; mp.matsq = 1;
    gemm_diff<<<dim3(8,8),256,0,stream>>>(mp);
  }
  k_pack_x<<<(NT*ROWS+255)/256,256,0,stream>>>(inputs, xenc);
  const int fs[4]  = {65,128,65,128};
  const int xfs[4] = {1,64,1,64};
  for (int i=0;i<4;i++) {
    k_split_w<<<(5*fs[i]*128+255)/256,256,0,stream>>>(gwp[i], gwh[i], gwx[i], fs[i], xfs[i], 128);
    k_split_w<<<(5*fs[i]*64 +255)/256,256,0,stream>>>(cwp[i], cwh[i], cwx[i], fs[i], xfs[i], 64);
  }

  auto run_cell = [&](const f16* x16, int xf, f16* h16c, float* h32c, int wi) {
    // diffusion of h (and x)
    DiffP dp{};
    dp.A = W16; dp.K = 1024; dp.matsq = 0;
    dp.z1 = h16c; dp.ldz1 = 4096; dp.nct1 = 32; dp.o1 = Dh; dp.ldo1 = 4096;
    if (xf == 64) { dp.z2 = x16; dp.ldz2 = 4096; dp.nct2 = 32; dp.o2 = Dx;  dp.ldo2 = 4096; dp.cv2 = 128; }
    else          { dp.z2 = x16; dp.ldz2 = 64;   dp.nct2 = 1;  dp.o2 = Dx0; dp.ldo2 = 64;   dp.cv2 = 64;  }
    gemm_diff<<<dim3(32, dp.nct1 + dp.nct2), 256, 0, stream>>>(dp);
    // gate: ru = sigmoid(...); rh = r*h; store u
    CellP gp{};
    gp.ta.p[0] = h16c; for (int q=1;q<5;q++) gp.ta.p[q] = Dh + (long)(q-1)*SLOT;
    gp.wa = gwh[wi]; gp.bias = gbp[wi];
    gp.h32in = h32c; gp.rh = rh; gp.u32 = u32;
    if (xf == 64) {
      gp.nseg = 2; gp.xf1 = 0;
      gp.tb.p[0] = x16; for (int q=1;q<5;q++) gp.tb.p[q] = Dx + (long)(q-1)*SLOT;
      gp.wb = gwx[wi];
    } else {
      gp.nseg = 1; gp.xf1 = 1;
      gp.xq.p[0] = x16; for (int q=1;q<5;q++) gp.xq.p[q] = Dx0 + (long)(q-1)*ROWS;
      gp.wx0 = gwx[wi];
    }
    cell_gemm<128,1><<<512, 256, 0, stream>>>(gp);
    // diffusion of rh (reuses Dh slots; Dx untouched)
    DiffP dp2{};
    dp2.A = W16; dp2.K = 1024; dp2.matsq = 0;
    dp2.z1 = rh; dp2.ldz1 = 4096; dp2.nct1 = 32; dp2.o1 = Dh; dp2.ldo1 = 4096;
    dp2.nct2 = 0;
    gemm_diff<<<dim3(32, 32), 256, 0, stream>>>(dp2);
    // candidate + GRU update
    CellP cp{};
    cp.ta.p[0] = rh; for (int q=1;q<5;q++) cp.ta.p[q] = Dh + (long)(q-1)*SLOT;
    cp.wa = cwh[wi]; cp.bias = cbp[wi];
    cp.u32 = u32; cp.h32io = h32c; cp.h16io = h16c;
    if (xf == 64) {
      cp.nseg = 2; cp.xf1 = 0;
      cp.tb.p[0] = x16; for (int q=1;q<5;q++) cp.tb.p[q] = Dx + (long)(q-1)*SLOT;
      cp.wb = cwx[wi];
    } else {
      cp.nseg = 1; cp.xf1 = 1;
      cp.xq.p[0] = x16; for (int q=1;q<5;q++) cp.xq.p[q] = Dx0 + (long)(q-1)*ROWS;
      cp.wx0 = cwx[wi];
    }
    cell_gemm<64,0><<<512, 256, 0, stream>>>(cp);
  };

  for (int t=0;t<NT;t++) {
    run_cell(xenc + (long)t*ROWS, 1, h16[0], h32[0], 0);
    run_cell(h16[0],             64, h16[1], h32[1], 1);
  }
  for (int s=0;s<NHOR;s++) {
    run_cell(xdec,   1, h16[0], h32[0], 2);
    run_cell(h16[0], 64, h16[1], h32[1], 3);
    k_proj<<<ROWS/256, 256, 0, stream>>>(h32[1], pw, pb, out + (long)s*ROWS, xdec);
  }
}

// Round 2
// 10926.048 us; speedup vs baseline: 1.1407x; 1.1407x over previous
//
#include <hip/hip_runtime.h>

typedef _Float16 f16;
typedef _Float16 f16x4 __attribute__((ext_vector_type(4)));
typedef _Float16 f16x8 __attribute__((ext_vector_type(8)));
typedef float    f32x4 __attribute__((ext_vector_type(4)));

#define NN 1024
#define NT 12
#define NHOR 12
#define ROWS (NN*64)                      // 65536 (n*64+b)
static const long SLOT = (long)NN*4096;   // one diffusion slot (n, b, u) = 4M halves

// ---- swizzled LDS addressing: tile rows of 32 halves (64B), 16B-chunk XOR (chunk ^ row&3)
__device__ __forceinline__ int swz(int row, int halfoff) {
  return row*32 + ((((halfoff>>3) ^ row) & 3)<<3) + (halfoff&7);
}

// stage NR rows x 32 halves from src (row stride ldk halves, k-window at k0) into lds,
// linear dest, source pre-swizzled at 16B granularity.
template<int NR>
__device__ __forceinline__ void stage_rows(f16* lds, const f16* src, long ldk, int k0, int w, int l) {
  const int r4 = l>>2, c4 = l&3;
  #pragma unroll
  for (int ic=0; ic<NR/64; ++ic) {
    const int row = (w + ic*4)*16 + r4;
    const f16* g = src + (long)row*ldk + k0 + ((c4 ^ (row&3))<<3);
    f16* d = lds + row*32 + c4*8;
    __builtin_amdgcn_global_load_lds((const __attribute__((address_space(1))) void*)g,
                                     (__attribute__((address_space(3))) void*)d, 16, 0, 0);
  }
}

__device__ __forceinline__ f16x8 frag(const f16* lds, int row, int lk) {
  f16x4 lo = *(const f16x4*)&lds[swz(row, lk)];
  f16x4 hi = *(const f16x4*)&lds[swz(row, 16+lk)];
  f16x8 r; r[0]=lo[0];r[1]=lo[1];r[2]=lo[2];r[3]=lo[3];
  r[4]=hi[0];r[5]=hi[1];r[6]=hi[2];r[7]=hi[3];
  return r;
}

// ---------------------------------------------------------------- diffusion GEMM (A·B^T)
// out[c][col] = sum_k A[c][k]*B[col][k]; A rows: activations-transposed; B rows: W (natural).
struct DiffP {
  const f16* A0; const f16* A1; int nt0;   // row-tile < nt0 -> A0 else A1
  const f16* B;                            // [Ncols][1024] row-major
  f16* out0; f16* out1;                    // act-mode q-slot bases (h-part / x-part)
  long ldo1;                               // wsq-mode output ld
  int mode_x;                              // x-part: 0 = act slots (SLOT), 2 = Dx0 slots (ROWS)
  int wsq;                                 // 1: out = 2*acc - I to out0[rg*ldo1+cg]
};

__global__ __launch_bounds__(256) void gemm_diff(DiffP p) {
  __shared__ f16 As[128*32];
  __shared__ f16 Bs[128*32];
  const int tid=threadIdx.x, l=tid&63, w=tid>>6;
  const int rq=l>>4, ro=l&15, lk=rq*4;
  const int rt=blockIdx.x, ct=blockIdx.y;
  const int part = (rt >= p.nt0);
  const int rtl  = part ? (rt - p.nt0) : rt;
  const f16* Abase = (part ? p.A1 : p.A0) + (long)rtl*128*1024;
  const f16* Bbase = p.B + (long)ct*128*1024;
  const int wm=(w>>1)*64, wc=(w&1)*64;
  f32x4 acc[4][4] = {};
  for (int k0=0; k0<1024; k0+=32) {
    stage_rows<128>(As, Abase, 1024, k0, w, l);
    stage_rows<128>(Bs, Bbase, 1024, k0, w, l);
    __syncthreads();
    f16x8 a[4], b[4];
    #pragma unroll
    for (int i=0;i<4;i++) a[i] = frag(As, wm + i*16 + ro, lk);
    #pragma unroll
    for (int j=0;j<4;j++) b[j] = frag(Bs, wc + j*16 + ro, lk);
    #pragma unroll
    for (int i=0;i<4;i++)
      #pragma unroll
      for (int j=0;j<4;j++)
        acc[i][j] = __builtin_amdgcn_mfma_f32_16x16x32_f16(a[i], b[j], acc[i][j], 0,0,0);
    __syncthreads();
  }
  const int c0 = ct*128;
  if (p.wsq) {
    #pragma unroll
    for (int i=0;i<4;i++)
      #pragma unroll
      for (int j=0;j<4;j++) {
        const int cg = c0 + wc + j*16 + ro;
        #pragma unroll
        for (int e=0;e<4;e++) {
          const long rg = (long)rt*128 + wm + i*16 + rq*4 + e;
          float v = 2.f*acc[i][j][e] - ((rg==cg)?1.f:0.f);
          p.out0[rg*p.ldo1 + cg] = (f16)v;
        }
      }
    return;
  }
  f16* ob = part ? p.out1 : p.out0;
  const int mode = part ? p.mode_x : 0;
  #pragma unroll
  for (int i=0;i<4;i++) {
    const int crow = rtl*128 + wm + i*16 + rq*4;
    #pragma unroll
    for (int j=0;j<4;j++) {
      const int col = c0 + wc + j*16 + ro;
      const int q = col>>10, n = col&1023;
      f16x4 sv;
      #pragma unroll
      for (int e=0;e<4;e++) sv[e] = (f16)acc[i][j][e];
      if (mode == 0)          *(f16x4*)(ob + (long)q*SLOT + (long)n*4096 + crow) = sv;
      else if (crow < 64)     *(f16x4*)(ob + (long)q*ROWS + n*64 + crow) = sv;
    }
  }
}

// ---------------------------------------------------------------- cell GEMMs
struct Tab5 { const f16* p[5]; };
struct CellP {
  Tab5 ta, tb, xq;
  const f16 *wa, *wb, *wx0;   // wa/wb transposed: [O][320]; wx0: [5][O]
  const float* bias;
  const float* h32in;
  f16* rh; float* u32;
  float* h32io; f16* h16io;
  int nseg, xf1;
};

template<int O, int GATE>
__global__ __launch_bounds__(256) void cell_gemm(CellP p) {
  constexpr int FC = O/32;
  __shared__ f16 As[128*32];
  __shared__ f16 Bs[O*32];
  const int tid=threadIdx.x, l=tid&63, w=tid>>6;
  const int rq=l>>4, ro=l&15, lk=rq*4;
  const int wm=(w>>1)*64, wc=(w&1)*(O/2);
  f32x4 acc[4][FC] = {};
  const long r0 = (long)blockIdx.x*128;
  const int Ktot = p.nseg*320;
  for (int kg=0; kg<Ktot; kg+=32) {
    const int seg = (kg>=320) ? 1 : 0;
    const int kk  = kg - seg*320;
    const int q = kk>>6, kq = kk&63;
    const f16* asrc = (seg ? p.tb.p[q] : p.ta.p[q]) + r0*64;
    const f16* wsrc = seg ? p.wb : p.wa;
    stage_rows<128>(As, asrc, 64, kq, w, l);
    stage_rows<O>(Bs, wsrc, 320, kk, w, l);
    __syncthreads();
    f16x8 a[4], b[FC];
    #pragma unroll
    for (int i=0;i<4;i++) a[i] = frag(As, wm + i*16 + ro, lk);
    #pragma unroll
    for (int j=0;j<FC;j++) b[j] = frag(Bs, wc + j*16 + ro, lk);
    #pragma unroll
    for (int i=0;i<4;i++)
      #pragma unroll
      for (int j=0;j<FC;j++)
        acc[i][j] = __builtin_amdgcn_mfma_f32_16x16x32_f16(a[i], b[j], acc[i][j], 0,0,0);
    __syncthreads();
  }
  #pragma unroll
  for (int i=0;i<4;i++) {
    #pragma unroll
    for (int e=0;e<4;e++) {
      const long rg = r0 + wm + i*16 + rq*4 + e;
      float xv[5];
      if (p.xf1) {
        #pragma unroll
        for (int q2=0;q2<5;q2++) xv[q2] = (float)p.xq.p[q2][rg];
      }
      #pragma unroll
      for (int j=0;j<FC;j++) {
        const int col = wc + j*16 + ro;
        float v = acc[i][j][e] + p.bias[col];
        if (p.xf1) {
          #pragma unroll
          for (int q2=0;q2<5;q2++) v += xv[q2] * (float)p.wx0[q2*O + col];
        }
        if (GATE) {
          const float s = 1.f/(1.f + __expf(-v));
          if (col < 64) p.rh[rg*64 + col] = (f16)(s * p.h32in[rg*64 + col]);
          else          p.u32[rg*64 + (col-64)] = s;
        } else {
          const float cc = tanhf(v);
          const float u  = p.u32[rg*64 + col];
          const float h  = p.h32io[rg*64 + col];
          const float hn = u*h + (1.f-u)*cc;
          p.h32io[rg*64 + col] = hn;
          p.h16io[rg*64 + col] = (f16)hn;
        }
      }
    }
  }
}

// ---------------------------------------------------------------- transpose: in[R][C] -> out[C][R]
__global__ __launch_bounds__(256) void k_transpose(const f16* in, f16* out, int R, int C) {
  __shared__ f16 T[64*66];
  const long rb = (long)blockIdx.x*64, cb = (long)blockIdx.y*64;
  const int t = threadIdx.x;
  #pragma unroll
  for (int it=0; it<2; ++it) {
    const int r = (t>>3) + it*32, c8 = (t&7)*8;
    f16x8 v = *(const f16x8*)(in + (rb+r)*C + cb + c8);
    *(f16x8*)&T[r*66 + c8] = v;
  }
  __syncthreads();
  #pragma unroll
  for (int it=0; it<2; ++it) {
    const int c = (t>>3) + it*32, r8 = (t&7)*8;
    f16x8 v;
    #pragma unroll
    for (int j=0;j<8;j++) v[j] = T[(r8+j)*66 + c];
    *(f16x8*)(out + (cb+c)*R + rb + r8) = v;
  }
}

// ---------------------------------------------------------------- small kernels
__global__ void k_cast_sup(const float* s, f16* W) {
  long i = (long)blockIdx.x*256 + threadIdx.x;
  if (i >= 2LL*NN*NN) return;
  long ss = (i >= (long)NN*NN) ? 1 : 0;
  long off = i - ss*(long)NN*NN;
  W[ss*2*(long)NN*NN + off] = (f16)s[i];
}

__global__ void k_pack_x(const float* in, f16* xe, f16* xet) {
  int i = blockIdx.x*256 + threadIdx.x;
  if (i >= NT*ROWS) return;
  int t = i / ROWS, r = i % ROWS, n = r>>6, b = r&63;
  float v = in[(long)b*NN*NT + (long)n*NT + t];
  xe[i] = (f16)v;
  xet[(long)t*128*1024 + (long)b*1024 + n] = (f16)v;
}

// src [5][f][O] -> wh_t [O][320] (h rows); x rows -> wx_t [O][320] (xf=64) or wx0 [5][O] (xf=1)
__global__ void k_split_w_t(const float* src, f16* wh_t, f16* wxA, int f, int xf, int O) {
  int i = blockIdx.x*256 + threadIdx.x;
  if (i >= 5*f*O) return;
  int o = i % O, rr = i / O, q = rr / f, ff = rr % f;
  f16 v = (f16)src[i];
  if (ff < xf) {
    if (xf == 1) wxA[q*O + o] = v;
    else         wxA[(long)o*320 + q*64 + ff] = v;
  } else {
    wh_t[(long)o*320 + q*64 + (ff - xf)] = v;
  }
}

__global__ void k_proj(const float* h32, const float* pw, const float* pb,
                       float* out, f16* xdec, f16* xdect) {
  int r = blockIdx.x*256 + threadIdx.x;
  if (r >= ROWS) return;
  float acc = pb[0];
  const float* hp = h32 + (long)r*64;
  #pragma unroll
  for (int k=0;k<64;k++) acc += hp[k]*pw[k];
  int n = r>>6, b = r&63;
  out[(long)b*NN + n] = acc;
  xdec[r] = (f16)acc;
  xdect[(long)b*1024 + n] = (f16)acc;
}

// ---------------------------------------------------------------- driver
extern "C" void kernel_launch(void* const* d_in, const int* in_sizes, int n_in,
                              void* d_out, int out_size, void* d_ws, size_t ws_size,
                              hipStream_t stream) {
  (void)in_sizes; (void)n_in; (void)out_size; (void)ws_size;
  const float* inputs = (const float*)d_in[0];
  const float* sup    = (const float*)d_in[1];
  const float* gwp[4] = {(const float*)d_in[2], (const float*)d_in[6], (const float*)d_in[10], (const float*)d_in[14]};
  const float* gbp[4] = {(const float*)d_in[3], (const float*)d_in[7], (const float*)d_in[11], (const float*)d_in[15]};
  const float* cwp[4] = {(const float*)d_in[4], (const float*)d_in[8], (const float*)d_in[12], (const float*)d_in[16]};
  const float* cbp[4] = {(const float*)d_in[5], (const float*)d_in[9], (const float*)d_in[13], (const float*)d_in[17]};
  const float* pw = (const float*)d_in[18];
  const float* pb = (const float*)d_in[19];
  float* out = (float*)d_out;

  char* base = (char*)d_ws; size_t off = 0;
  auto alloc = [&](size_t bytes)->void* { void* p = base + off; off += (bytes + 255) & ~(size_t)255; return p; };
  f16* W16    = (f16*)alloc(4LL*NN*NN*2);        // [A0, 2A0^2-I, A1, 2A1^2-I], rows [q*1024+n][m]
  f16* xenc   = (f16*)alloc((long)NT*ROWS*2);
  f16* xenct  = (f16*)alloc((long)NT*128*1024*2);  // padded to 128 rows per t
  f16* xdec   = (f16*)alloc((long)ROWS*2);
  f16* xdect  = (f16*)alloc(128L*1024*2);
  f16*  h16[2]  = {(f16*)alloc((long)ROWS*64*2),  (f16*)alloc((long)ROWS*64*2)};
  f16*  hhat[2] = {(f16*)alloc(4096L*1024*2),     (f16*)alloc(4096L*1024*2)};
  float* h32[2] = {(float*)alloc((long)ROWS*64*4), (float*)alloc((long)ROWS*64*4)};
  float* u32 = (float*)alloc((long)ROWS*64*4);
  f16* rh    = (f16*)alloc((long)ROWS*64*2);
  f16* rhhat = (f16*)alloc(4096L*1024*2);
  f16* Dh    = (f16*)alloc(4*SLOT*2);
  f16* Dx    = (f16*)alloc(4*SLOT*2);
  f16* Dx0   = (f16*)alloc(4LL*ROWS*2);
  f16 *gwh[4], *gwx[4], *cwh[4], *cwx[4];
  for (int i=0;i<4;i++) {
    gwh[i]=(f16*)alloc(128L*320*2); gwx[i]=(f16*)alloc(128L*320*2);
    cwh[i]=(f16*)alloc(64L*320*2);  cwx[i]=(f16*)alloc(64L*320*2);
  }

  hipMemsetAsync(h16[0], 0, (long)ROWS*64*2, stream);
  hipMemsetAsync(h16[1], 0, (long)ROWS*64*2, stream);
  hipMemsetAsync(hhat[0], 0, 4096L*1024*2, stream);
  hipMemsetAsync(hhat[1], 0, 4096L*1024*2, stream);
  hipMemsetAsync(h32[0], 0, (long)ROWS*64*4, stream);
  hipMemsetAsync(h32[1], 0, (long)ROWS*64*4, stream);
  hipMemsetAsync(xdec,   0, (long)ROWS*2, stream);
  hipMemsetAsync(xdect,  0, 128L*1024*2, stream);

  // setup: cast supports, build W^2 ops via transposed-A GEMM
  k_cast_sup<<<(2*NN*NN+255)/256, 256, 0, stream>>>(sup, W16);
  f16* At = Dh;   // scratch alias (Dh unused during setup)
  for (int s=0;s<2;s++)
    k_transpose<<<dim3(16,16),256,0,stream>>>(W16 + (long)s*2*NN*NN, At + (long)s*NN*NN, 1024, 1024);
  for (int s=0;s<2;s++) {
    DiffP mp{};
    mp.A0 = W16 + (long)s*2*NN*NN; mp.A1 = mp.A0; mp.nt0 = 8;
    mp.B  = At + (long)s*NN*NN;
    mp.out0 = W16 + ((long)s*2+1)*NN*NN; mp.ldo1 = 1024; mp.wsq = 1;
    gemm_diff<<<dim3(8,8),256,0,stream>>>(mp);
  }
  k_pack_x<<<(NT*ROWS+255)/256,256,0,stream>>>(inputs, xenc, xenct);
  const int fs[4]  = {65,128,65,128};
  const int xfs[4] = {1,64,1,64};
  for (int i=0;i<4;i++) {
    k_split_w_t<<<(5*fs[i]*128+255)/256,256,0,stream>>>(gwp[i], gwh[i], gwx[i], fs[i], xfs[i], 128);
    k_split_w_t<<<(5*fs[i]*64 +255)/256,256,0,stream>>>(cwp[i], cwh[i], cwx[i], fs[i], xfs[i], 64);
  }

  auto run_cell = [&](const f16* xraw, const f16* xhat, int xf,
                      f16* h16c, f16* hhatc, float* h32c, int wi) {
    // diffusion of h (+x)
    DiffP dp{};
    dp.A0 = hhatc; dp.nt0 = 32; dp.B = W16; dp.out0 = Dh;
    int gx;
    if (xf == 64) { dp.A1 = xhat; dp.out1 = Dx;  dp.mode_x = 0; gx = 64; }
    else          { dp.A1 = xhat; dp.out1 = Dx0; dp.mode_x = 2; gx = 33; }
    gemm_diff<<<dim3(gx, 32), 256, 0, stream>>>(dp);
    // gate
    CellP gp{};
    gp.ta.p[0] = h16c; for (int q=1;q<5;q++) gp.ta.p[q] = Dh + (long)(q-1)*SLOT;
    gp.wa = gwh[wi]; gp.bias = gbp[wi];
    gp.h32in = h32c; gp.rh = rh; gp.u32 = u32;
    if (xf == 64) {
      gp.nseg = 2; gp.xf1 = 0;
      gp.tb.p[0] = xraw; for (int q=1;q<5;q++) gp.tb.p[q] = Dx + (long)(q-1)*SLOT;
      gp.wb = gwx[wi];
    } else {
      gp.nseg = 1; gp.xf1 = 1;
      gp.xq.p[0] = xraw; for (int q=1;q<5;q++) gp.xq.p[q] = Dx0 + (long)(q-1)*ROWS;
      gp.wx0 = gwx[wi];
    }
    cell_gemm<128,1><<<512, 256, 0, stream>>>(gp);
    // transpose rh, diffuse
    k_transpose<<<dim3(16,64),256,0,stream>>>(rh, rhhat, 1024, 4096);
    DiffP dp2{};
    dp2.A0 = rhhat; dp2.A1 = rhhat; dp2.nt0 = 32; dp2.B = W16; dp2.out0 = Dh;
    gemm_diff<<<dim3(32, 32), 256, 0, stream>>>(dp2);
    // candidate + GRU update
    CellP cp{};
    cp.ta.p[0] = rh; for (int q=1;q<5;q++) cp.ta.p[q] = Dh + (long)(q-1)*SLOT;
    cp.wa = cwh[wi]; cp.bias = cbp[wi];
    cp.u32 = u32; cp.h32io = h32c; cp.h16io = h16c;
    if (xf == 64) {
      cp.nseg = 2; cp.xf1 = 0;
      cp.tb.p[0] = xraw; for (int q=1;q<5;q++) cp.tb.p[q] = Dx + (long)(q-1)*SLOT;
      cp.wb = cwx[wi];
    } else {
      cp.nseg = 1; cp.xf1 = 1;
      cp.xq.p[0] = xraw; for (int q=1;q<5;q++) cp.xq.p[q] = Dx0 + (long)(q-1)*ROWS;
      cp.wx0 = cwx[wi];
    }
    cell_gemm<64,0><<<512, 256, 0, stream>>>(cp);
    // transpose updated h for next diffusion
    k_transpose<<<dim3(16,64),256,0,stream>>>(h16c, hhatc, 1024, 4096);
  };

  for (int t=0;t<NT;t++) {
    run_cell(xenc + (long)t*ROWS, xenct + (long)t*128*1024, 1, h16[0], hhat[0], h32[0], 0);
    run_cell(h16[0], hhat[0],                              64, h16[1], hhat[1], h32[1], 1);
  }
  for (int s=0;s<NHOR;s++) {
    run_cell(xdec,   xdect,   1, h16[0], hhat[0], h32[0], 2);
    run_cell(h16[0], hhat[0],64, h16[1], hhat[1], h32[1], 3);
    k_proj<<<ROWS/256, 256, 0, stream>>>(h32[1], pw, pb, out + (long)s*ROWS, xdec, xdect);
  }
}